// Round 4
// baseline (612.190 us; speedup 1.0000x reference)
//
#include <hip/hip_runtime.h>
#include <hip/hip_bf16.h>

#define BB 4
#define CC 256
#define NN 4096
#define AC2 64

typedef __attribute__((ext_vector_type(4))) float f32x4;
typedef __attribute__((ext_vector_type(8))) short bf16x8;

__device__ __forceinline__ short f2bf(float f) {
    unsigned u = __builtin_bit_cast(unsigned, f);
    u = u + 0x7FFFu + ((u >> 16) & 1u);
    return (short)(u >> 16);
}

// ---------------- Kernel 0: convert weights to bf16 Wb[384][256] ----------------
// rows 0-63 = Wq, 64-127 = Wk, 128-383 = Wv. Row-major, k=c contiguous -> direct
// A-fragment loads in qkv_kernel (L2-resident, 192 KB).
__global__ __launch_bounds__(256) void prep_kernel(
    const float* __restrict__ Wq, const float* __restrict__ Wk,
    const float* __restrict__ Wv, short* __restrict__ Wb)
{
    const int idx = (blockIdx.x * 256 + threadIdx.x) * 4;  // 96 blocks cover 98304
    const int o = idx >> 8, c = idx & 255;
    const float* row = (o < 64) ? (Wq + o * CC)
                     : (o < 128) ? (Wk + (o - 64) * CC)
                                 : (Wv + (o - 128) * CC);
    float4 v = *(const float4*)&row[c];
    short4 s4;
    s4.x = f2bf(v.x); s4.y = f2bf(v.y); s4.z = f2bf(v.z); s4.w = f2bf(v.w);
    *(short4*)&Wb[idx] = s4;
}

// ---------------- Kernel 1: QKV projection ----------------
// 512 thr (8 waves), n-tile 32, grid B*128. W frags direct from global bf16;
// only X^T staged in LDS.
__global__ __launch_bounds__(512) void qkv_kernel(
    const float* __restrict__ x, const short* __restrict__ Wb,
    const float* __restrict__ bq, const float* __restrict__ bk,
    const float* __restrict__ bv,
    short* __restrict__ Qt, short* __restrict__ Kt, short* __restrict__ V)
{
    __shared__ __align__(16) short Xl[32 * 72];
    const int bid0 = blockIdx.x;
    const int bid = ((bid0 & 7) << 6) | (bid0 >> 3);  // XCD swizzle (512 % 8 == 0)
    const int b = bid >> 7;
    const int n0 = (bid & 127) << 5;
    const int tid = threadIdx.x;
    const int lane = tid & 63, w = tid >> 6;
    const int l15 = lane & 15, lh = lane >> 4;

    f32x4 acc[3][2];
#pragma unroll
    for (int i = 0; i < 3; ++i)
#pragma unroll
        for (int j = 0; j < 2; ++j) acc[i][j] = (f32x4){0.f, 0.f, 0.f, 0.f};

    for (int ck = 0; ck < 4; ++ck) {
        const int c0 = ck << 6;
        // prefetch this wave's W fragments (48 out-rows) straight from global
        bf16x8 Af[3][2];
#pragma unroll
        for (int of = 0; of < 3; ++of)
#pragma unroll
            for (int ks = 0; ks < 2; ++ks)
                Af[of][ks] = *(const bf16x8*)&Wb[(size_t)(w * 48 + of * 16 + l15) * CC +
                                                 c0 + ks * 32 + (lh << 3)];
        // stage X^T tile [32 n][64 c] (one float4 per thread)
        {
            const int cr = tid >> 3, q4 = tid & 7;
            float4 v = *(const float4*)&x[((size_t)(b * CC + c0 + cr)) * NN + n0 + q4 * 4];
            Xl[(q4 * 4 + 0) * 72 + cr] = f2bf(v.x);
            Xl[(q4 * 4 + 1) * 72 + cr] = f2bf(v.y);
            Xl[(q4 * 4 + 2) * 72 + cr] = f2bf(v.z);
            Xl[(q4 * 4 + 3) * 72 + cr] = f2bf(v.w);
        }
        __syncthreads();
#pragma unroll
        for (int ks = 0; ks < 2; ++ks) {
            const int co = ks * 32 + (lh << 3);
            bf16x8 Bf[2];
#pragma unroll
            for (int nf = 0; nf < 2; ++nf)
                Bf[nf] = *(const bf16x8*)&Xl[(nf * 16 + l15) * 72 + co];
#pragma unroll
            for (int of = 0; of < 3; ++of)
#pragma unroll
                for (int nf = 0; nf < 2; ++nf)
                    acc[of][nf] = __builtin_amdgcn_mfma_f32_16x16x32_bf16(
                        Af[of][ks], Bf[nf], acc[of][nf], 0, 0, 0);
        }
        __syncthreads();
    }
    // epilogue: bias + convert + scatter
#pragma unroll
    for (int of = 0; of < 3; ++of) {
        const int obase = w * 48 + of * 16 + (lh << 2);
        float bias[4];
#pragma unroll
        for (int r = 0; r < 4; ++r) {
            int o = obase + r;
            bias[r] = (o < 64) ? bq[o] : (o < 128) ? bk[o - 64] : bv[o - 128];
        }
#pragma unroll
        for (int nf = 0; nf < 2; ++nf) {
            const int n = n0 + nf * 16 + l15;
            if (obase < 128) {
                short4 pk;
                pk.x = f2bf(acc[of][nf][0] + bias[0]);
                pk.y = f2bf(acc[of][nf][1] + bias[1]);
                pk.z = f2bf(acc[of][nf][2] + bias[2]);
                pk.w = f2bf(acc[of][nf][3] + bias[3]);
                short* dst = (obase < 64)
                    ? (Qt + ((size_t)b * NN + n) * AC2 + obase)
                    : (Kt + ((size_t)b * NN + n) * AC2 + (obase - 64));
                *(short4*)dst = pk;
            } else {
#pragma unroll
                for (int r = 0; r < 4; ++r) {
                    int o = obase + r - 128;
                    V[(((size_t)b * CC + o) * NN) + n] = f2bf(acc[of][nf][r] + bias[r]);
                }
            }
        }
    }
}

// ---------------- Kernel 2: column softmax stats ----------------
// t_j = m_j + ln(l_j); P = exp(S - t_j) in out_kernel.
__global__ __launch_bounds__(256) void stats_kernel(
    const short* __restrict__ Qt, const short* __restrict__ Kt,
    float* __restrict__ tArr)
{
    const int bid0 = blockIdx.x;
    const int bid = ((bid0 & 7) << 7) | (bid0 >> 3);  // XCD swizzle (1024 % 8 == 0)
    const int b = bid >> 8;
    const int j0 = (bid & 255) << 4;
    const int tid = threadIdx.x;
    const int lane = tid & 63, w = tid >> 6;

    bf16x8 Bf[2];
#pragma unroll
    for (int ks = 0; ks < 2; ++ks)
        Bf[ks] = *(const bf16x8*)&Kt[((size_t)b * NN + j0 + (lane & 15)) * AC2 +
                                     ks * 32 + ((lane >> 4) << 3)];

    float m_run = -INFINITY, l_run = 0.f;
    for (int ii = 0; ii < 16; ++ii) {
        const int i0 = w * 1024 + ii * 64;
        f32x4 s[4];
#pragma unroll
        for (int f = 0; f < 4; ++f) {
            const size_t rowA = (size_t)b * NN + i0 + f * 16 + (lane & 15);
            bf16x8 A0 = *(const bf16x8*)&Qt[rowA * AC2 + ((lane >> 4) << 3)];
            bf16x8 A1 = *(const bf16x8*)&Qt[rowA * AC2 + 32 + ((lane >> 4) << 3)];
            f32x4 t = (f32x4){0.f, 0.f, 0.f, 0.f};
            t = __builtin_amdgcn_mfma_f32_16x16x32_bf16(A0, Bf[0], t, 0, 0, 0);
            t = __builtin_amdgcn_mfma_f32_16x16x32_bf16(A1, Bf[1], t, 0, 0, 0);
            s[f] = t;
        }
        float mx = s[0][0];
#pragma unroll
        for (int f = 0; f < 4; ++f)
#pragma unroll
            for (int r = 0; r < 4; ++r) mx = fmaxf(mx, s[f][r]);
        const float m_new = fmaxf(m_run, mx);
        float add = 0.f;
#pragma unroll
        for (int f = 0; f < 4; ++f)
#pragma unroll
            for (int r = 0; r < 4; ++r) add += __expf(s[f][r] - m_new);
        l_run = l_run * __expf(m_run - m_new) + add;
        m_run = m_new;
    }
#pragma unroll
    for (int off = 16; off <= 32; off <<= 1) {
        float m2 = __shfl_xor(m_run, off);
        float l2 = __shfl_xor(l_run, off);
        float mm = fmaxf(m_run, m2);
        l_run = l_run * __expf(m_run - mm) + l2 * __expf(m2 - mm);
        m_run = mm;
    }
    __shared__ float sm[4][16];
    __shared__ float sl[4][16];
    if (lane < 16) { sm[w][lane] = m_run; sl[w][lane] = l_run; }
    __syncthreads();
    if (tid < 16) {
        float m = sm[0][tid], l = sl[0][tid];
#pragma unroll
        for (int q = 1; q < 4; ++q) {
            float m2 = sm[q][tid], l2 = sl[q][tid];
            float mm = fmaxf(m, m2);
            l = l * __expf(m - mm) + l2 * __expf(m2 - mm);
            m = mm;
        }
        tArr[(size_t)b * NN + j0 + tid] = m + __logf(l);
    }
}

// ---------------- Kernel 3: P = exp(S - t), O = P @ V^T, residual ----------------
// Block = (b, 64-row i tile, 64-col c strip); grid B*64*4 = 1024 (16 waves/CU).
// Wave w owns S-rows [16w,16w+16) AND their PV for the block's c-strip ->
// P tile is wave-private -> NO barriers in the main loop.
__global__ __launch_bounds__(256) void out_kernel(
    const short* __restrict__ Qt, const short* __restrict__ Kt,
    const short* __restrict__ V,
    const float* __restrict__ tArr,
    const float* __restrict__ x, const float* __restrict__ gamma,
    float* __restrict__ out)
{
    __shared__ __align__(16) short Pl[4 * 16 * 72];   // per-wave 16x64 bf16, pitch 72
    __shared__ __align__(16) float Pf[4 * 16 * 69];   // epilogue transpose, pitch 69
    const int bid0 = blockIdx.x;
    const int bid = ((bid0 & 7) << 7) | (bid0 >> 3);  // XCD swizzle (1024 % 8 == 0)
    const int cs = bid & 3;
    const int itile = (bid >> 2) & 63;
    const int b = bid >> 8;
    const int i0 = itile << 6, c0 = cs << 6;
    const int tid = threadIdx.x;
    const int lane = tid & 63, w = tid >> 6;
    const int l15 = lane & 15, lh = lane >> 4;
    const int iw = i0 + (w << 4);
    short* Plw = Pl + w * (16 * 72);

    const short* Ktb = Kt + (size_t)b * NN * AC2;
    const float* tb = tArr + (size_t)b * NN;
    const short* Vb = V + ((size_t)b * CC + c0) * NN;

    bf16x8 Aq[2];
#pragma unroll
    for (int ks = 0; ks < 2; ++ks)
        Aq[ks] = *(const bf16x8*)&Qt[((size_t)b * NN + iw + l15) * AC2 +
                                     ks * 32 + (lh << 3)];

    f32x4 acc[4];
#pragma unroll
    for (int i = 0; i < 4; ++i) acc[i] = (f32x4){0.f, 0.f, 0.f, 0.f};

    for (int jt = 0; jt < 64; ++jt) {
        const int j0 = jt * 64;
        // S phase: rows iw..iw+16, cols j0..j0+64 -> P (wave-private LDS)
#pragma unroll
        for (int jf = 0; jf < 4; ++jf) {
            const int j = j0 + jf * 16 + l15;
            f32x4 s = (f32x4){0.f, 0.f, 0.f, 0.f};
#pragma unroll
            for (int ks = 0; ks < 2; ++ks) {
                bf16x8 Bf = *(const bf16x8*)&Ktb[(size_t)j * AC2 + ks * 32 + (lh << 3)];
                s = __builtin_amdgcn_mfma_f32_16x16x32_bf16(Aq[ks], Bf, s, 0, 0, 0);
            }
            const float tj = tb[j];
#pragma unroll
            for (int r = 0; r < 4; ++r)
                Plw[(lh * 4 + r) * 72 + jf * 16 + l15] = f2bf(__expf(s[r] - tj));
        }
        // PV phase (in-wave lgkmcnt ordering; no barrier)
#pragma unroll
        for (int ks = 0; ks < 2; ++ks) {
            const int jj = j0 + ks * 32 + (lh << 3);
            bf16x8 Ap = *(const bf16x8*)&Plw[l15 * 72 + ks * 32 + (lh << 3)];
#pragma unroll
            for (int cf = 0; cf < 4; ++cf) {
                bf16x8 Bv = *(const bf16x8*)&Vb[(size_t)(cf * 16 + l15) * NN + jj];
                acc[cf] = __builtin_amdgcn_mfma_f32_16x16x32_bf16(Ap, Bv, acc[cf], 0, 0, 0);
            }
        }
    }
    // epilogue: transpose acc via wave-private LDS, write 16B granules
    float* Pfw = Pf + w * (16 * 69);
#pragma unroll
    for (int cf = 0; cf < 4; ++cf)
#pragma unroll
        for (int r = 0; r < 4; ++r)
            Pfw[(lh * 4 + r) * 69 + cf * 16 + l15] = acc[cf][r];
    const float g = gamma[0];
    const size_t obase = ((size_t)(b * CC + c0 + lane)) * NN + iw;
#pragma unroll
    for (int e4 = 0; e4 < 4; ++e4) {
        float4 v;
        v.x = Pfw[(e4 * 4 + 0) * 69 + lane];
        v.y = Pfw[(e4 * 4 + 1) * 69 + lane];
        v.z = Pfw[(e4 * 4 + 2) * 69 + lane];
        v.w = Pfw[(e4 * 4 + 3) * 69 + lane];
        float4 xv = *(const float4*)&x[obase + e4 * 4];
        float4 o;
        o.x = g * v.x + xv.x;
        o.y = g * v.y + xv.y;
        o.z = g * v.z + xv.z;
        o.w = g * v.w + xv.w;
        *(float4*)&out[obase + e4 * 4] = o;
    }
}

extern "C" void kernel_launch(void* const* d_in, const int* in_sizes, int n_in,
                              void* d_out, int out_size, void* d_ws, size_t ws_size,
                              hipStream_t stream) {
    const float* x     = (const float*)d_in[0];
    const float* Wq    = (const float*)d_in[1];
    const float* bq    = (const float*)d_in[2];
    const float* Wk    = (const float*)d_in[3];
    const float* bk    = (const float*)d_in[4];
    const float* Wv    = (const float*)d_in[5];
    const float* bv    = (const float*)d_in[6];
    const float* gamma = (const float*)d_in[7];
    float* out = (float*)d_out;

    short* Qt = (short*)d_ws;                            // [B][N][64] bf16 (2 MB)
    short* Kt = Qt + (size_t)BB * NN * AC2;              // [B][N][64] bf16 (2 MB)
    short* V  = Kt + (size_t)BB * NN * AC2;              // [B][C][N]  bf16 (8 MB)
    float* tArr = (float*)(V + (size_t)BB * CC * NN);    // [B][N]     f32  (64 KB)
    short* Wb = (short*)(tArr + (size_t)BB * NN);        // [384][256] bf16 (192 KB)

    prep_kernel<<<96, 256, 0, stream>>>(Wq, Wk, Wv, Wb);
    qkv_kernel<<<BB * 128, 512, 0, stream>>>(x, Wb, bq, bk, bv, Qt, Kt, V);
    stats_kernel<<<BB * 256, 256, 0, stream>>>(Qt, Kt, tArr);
    out_kernel<<<BB * 256, 256, 0, stream>>>(Qt, Kt, V, tArr, x, gamma, out);
}

// Round 5
// 338.201 us; speedup vs baseline: 1.8101x; 1.8101x over previous
//
#include <hip/hip_runtime.h>
#include <hip/hip_bf16.h>

#define BB 4
#define CC 256
#define NN 4096
#define AC2 64
#define PP 76   // P-tile LDS pitch (shorts): 152 B rows -> lh-groups land on distinct banks

typedef __attribute__((ext_vector_type(4))) float f32x4;
typedef __attribute__((ext_vector_type(8))) short bf16x8;

__device__ __forceinline__ short f2bf(float f) {
    unsigned u = __builtin_bit_cast(unsigned, f);
    u = u + 0x7FFFu + ((u >> 16) & 1u);
    return (short)(u >> 16);
}

// ---------------- Kernel 0: convert weights to bf16 Wb[384][256] ----------------
__global__ __launch_bounds__(256) void prep_kernel(
    const float* __restrict__ Wq, const float* __restrict__ Wk,
    const float* __restrict__ Wv, short* __restrict__ Wb)
{
    const int idx = (blockIdx.x * 256 + threadIdx.x) * 4;  // 96 blocks cover 98304
    const int o = idx >> 8, c = idx & 255;
    const float* row = (o < 64) ? (Wq + o * CC)
                     : (o < 128) ? (Wk + (o - 64) * CC)
                                 : (Wv + (o - 128) * CC);
    float4 v = *(const float4*)&row[c];
    short4 s4;
    s4.x = f2bf(v.x); s4.y = f2bf(v.y); s4.z = f2bf(v.z); s4.w = f2bf(v.w);
    *(short4*)&Wb[idx] = s4;
}

// ---------------- Kernel 1: QKV projection (unchanged from R2) ----------------
__global__ __launch_bounds__(512) void qkv_kernel(
    const float* __restrict__ x, const short* __restrict__ Wb,
    const float* __restrict__ bq, const float* __restrict__ bk,
    const float* __restrict__ bv,
    short* __restrict__ Qt, short* __restrict__ Kt, short* __restrict__ V)
{
    __shared__ __align__(16) short Xl[32 * 72];
    const int bid0 = blockIdx.x;
    const int bid = ((bid0 & 7) << 6) | (bid0 >> 3);  // XCD swizzle (512 % 8 == 0)
    const int b = bid >> 7;
    const int n0 = (bid & 127) << 5;
    const int tid = threadIdx.x;
    const int lane = tid & 63, w = tid >> 6;
    const int l15 = lane & 15, lh = lane >> 4;

    f32x4 acc[3][2];
#pragma unroll
    for (int i = 0; i < 3; ++i)
#pragma unroll
        for (int j = 0; j < 2; ++j) acc[i][j] = (f32x4){0.f, 0.f, 0.f, 0.f};

    for (int ck = 0; ck < 4; ++ck) {
        const int c0 = ck << 6;
        bf16x8 Af[3][2];
#pragma unroll
        for (int of = 0; of < 3; ++of)
#pragma unroll
            for (int ks = 0; ks < 2; ++ks)
                Af[of][ks] = *(const bf16x8*)&Wb[(size_t)(w * 48 + of * 16 + l15) * CC +
                                                 c0 + ks * 32 + (lh << 3)];
        {
            const int cr = tid >> 3, q4 = tid & 7;
            float4 v = *(const float4*)&x[((size_t)(b * CC + c0 + cr)) * NN + n0 + q4 * 4];
            Xl[(q4 * 4 + 0) * 72 + cr] = f2bf(v.x);
            Xl[(q4 * 4 + 1) * 72 + cr] = f2bf(v.y);
            Xl[(q4 * 4 + 2) * 72 + cr] = f2bf(v.z);
            Xl[(q4 * 4 + 3) * 72 + cr] = f2bf(v.w);
        }
        __syncthreads();
#pragma unroll
        for (int ks = 0; ks < 2; ++ks) {
            const int co = ks * 32 + (lh << 3);
            bf16x8 Bf[2];
#pragma unroll
            for (int nf = 0; nf < 2; ++nf)
                Bf[nf] = *(const bf16x8*)&Xl[(nf * 16 + l15) * 72 + co];
#pragma unroll
            for (int of = 0; of < 3; ++of)
#pragma unroll
                for (int nf = 0; nf < 2; ++nf)
                    acc[of][nf] = __builtin_amdgcn_mfma_f32_16x16x32_bf16(
                        Af[of][ks], Bf[nf], acc[of][nf], 0, 0, 0);
        }
        __syncthreads();
    }
#pragma unroll
    for (int of = 0; of < 3; ++of) {
        const int obase = w * 48 + of * 16 + (lh << 2);
        float bias[4];
#pragma unroll
        for (int r = 0; r < 4; ++r) {
            int o = obase + r;
            bias[r] = (o < 64) ? bq[o] : (o < 128) ? bk[o - 64] : bv[o - 128];
        }
#pragma unroll
        for (int nf = 0; nf < 2; ++nf) {
            const int n = n0 + nf * 16 + l15;
            if (obase < 128) {
                short4 pk;
                pk.x = f2bf(acc[of][nf][0] + bias[0]);
                pk.y = f2bf(acc[of][nf][1] + bias[1]);
                pk.z = f2bf(acc[of][nf][2] + bias[2]);
                pk.w = f2bf(acc[of][nf][3] + bias[3]);
                short* dst = (obase < 64)
                    ? (Qt + ((size_t)b * NN + n) * AC2 + obase)
                    : (Kt + ((size_t)b * NN + n) * AC2 + (obase - 64));
                *(short4*)dst = pk;
            } else {
#pragma unroll
                for (int r = 0; r < 4; ++r) {
                    int o = obase + r - 128;
                    V[(((size_t)b * CC + o) * NN) + n] = f2bf(acc[of][nf][r] + bias[r]);
                }
            }
        }
    }
}

// ---------------- Kernel 2: column softmax stats (now with Q prefetch) ----------
__global__ __launch_bounds__(256) void stats_kernel(
    const short* __restrict__ Qt, const short* __restrict__ Kt,
    float* __restrict__ tArr)
{
    const int bid0 = blockIdx.x;
    const int bid = ((bid0 & 7) << 7) | (bid0 >> 3);  // XCD swizzle (1024 % 8 == 0)
    const int b = bid >> 8;
    const int j0 = (bid & 255) << 4;
    const int tid = threadIdx.x;
    const int lane = tid & 63, w = tid >> 6;
    const int l15 = lane & 15, lh = lane >> 4;
    const short* Qb = Qt + (size_t)b * NN * AC2;

    bf16x8 Bf[2];
#pragma unroll
    for (int ks = 0; ks < 2; ++ks)
        Bf[ks] = *(const bf16x8*)&Kt[((size_t)b * NN + j0 + l15) * AC2 +
                                     ks * 32 + (lh << 3)];

    bf16x8 A0[4], A1[4];
#pragma unroll
    for (int f = 0; f < 4; ++f) {
        const size_t rowA = (size_t)(w * 1024 + f * 16 + l15);
        A0[f] = *(const bf16x8*)&Qb[rowA * AC2 + (lh << 3)];
        A1[f] = *(const bf16x8*)&Qb[rowA * AC2 + 32 + (lh << 3)];
    }

    float m_run = -INFINITY, l_run = 0.f;
    for (int ii = 0; ii < 16; ++ii) {
        // prefetch next ii's Q fragments (wraps harmlessly on last iter)
        bf16x8 A0n[4], A1n[4];
        const int in0 = w * 1024 + ((ii + 1) & 15) * 64;
#pragma unroll
        for (int f = 0; f < 4; ++f) {
            const size_t rowA = (size_t)(in0 + f * 16 + l15);
            A0n[f] = *(const bf16x8*)&Qb[rowA * AC2 + (lh << 3)];
            A1n[f] = *(const bf16x8*)&Qb[rowA * AC2 + 32 + (lh << 3)];
        }
        f32x4 s[4];
#pragma unroll
        for (int f = 0; f < 4; ++f) {
            f32x4 t = (f32x4){0.f, 0.f, 0.f, 0.f};
            t = __builtin_amdgcn_mfma_f32_16x16x32_bf16(A0[f], Bf[0], t, 0, 0, 0);
            t = __builtin_amdgcn_mfma_f32_16x16x32_bf16(A1[f], Bf[1], t, 0, 0, 0);
            s[f] = t;
        }
        float mx = s[0][0];
#pragma unroll
        for (int f = 0; f < 4; ++f)
#pragma unroll
            for (int r = 0; r < 4; ++r) mx = fmaxf(mx, s[f][r]);
        const float m_new = fmaxf(m_run, mx);
        float add = 0.f;
#pragma unroll
        for (int f = 0; f < 4; ++f)
#pragma unroll
            for (int r = 0; r < 4; ++r) add += __expf(s[f][r] - m_new);
        l_run = l_run * __expf(m_run - m_new) + add;
        m_run = m_new;
#pragma unroll
        for (int f = 0; f < 4; ++f) { A0[f] = A0n[f]; A1[f] = A1n[f]; }
    }
#pragma unroll
    for (int off = 16; off <= 32; off <<= 1) {
        float m2 = __shfl_xor(m_run, off);
        float l2 = __shfl_xor(l_run, off);
        float mm = fmaxf(m_run, m2);
        l_run = l_run * __expf(m_run - mm) + l2 * __expf(m2 - mm);
        m_run = mm;
    }
    __shared__ float sm[4][16];
    __shared__ float sl[4][16];
    if (lane < 16) { sm[w][lane] = m_run; sl[w][lane] = l_run; }
    __syncthreads();
    if (tid < 16) {
        float m = sm[0][tid], l = sl[0][tid];
#pragma unroll
        for (int q = 1; q < 4; ++q) {
            float m2 = sm[q][tid], l2 = sl[q][tid];
            float mm = fmaxf(m, m2);
            l = l * __expf(m - mm) + l2 * __expf(m2 - mm);
            m = mm;
        }
        tArr[(size_t)b * NN + j0 + tid] = m + __logf(l);
    }
}

// ---------------- Kernel 3: P = exp(S-t), O = P @ V^T, residual ----------------
// Block = (b, 64-row i-tile, 128-col c-half): grid B*64*2 = 512 (2 blocks/CU).
// Wave w computes S rows [16w,16w+16) -> shared P (double-buffered, ONE raw
// barrier per jt, lgkm-only drain so K/V prefetch stays in flight); PV: each
// wave owns a 32-c strip, every P A-frag feeds 2 MFMAs, every V B-frag feeds 4.
__global__ __launch_bounds__(256) void out_kernel(
    const short* __restrict__ Qt, const short* __restrict__ Kt,
    const short* __restrict__ V,
    const float* __restrict__ tArr,
    const float* __restrict__ x, const float* __restrict__ gamma,
    float* __restrict__ out)
{
    __shared__ __align__(16) short Pl[2][64 * PP];   // 19456 B; reused by epilogue
    const int bid0 = blockIdx.x;
    const int bid = ((bid0 & 7) << 6) | (bid0 >> 3);  // XCD swizzle (512 % 8 == 0)
    const int cs = bid & 1;
    const int itile = (bid >> 1) & 63;
    const int b = bid >> 7;
    const int i0 = itile << 6, c0 = cs << 7;
    const int tid = threadIdx.x;
    const int lane = tid & 63, w = tid >> 6;
    const int l15 = lane & 15, lh = lane >> 4;
    const int iw = i0 + (w << 4);

    const short* Ktb = Kt + (size_t)b * NN * AC2;
    const float* tb  = tArr + (size_t)b * NN;
    const short* Vb  = V + ((size_t)b * CC + c0 + (w << 5)) * NN;  // wave's 32-c strip

    bf16x8 Aq[2];
#pragma unroll
    for (int ks = 0; ks < 2; ++ks)
        Aq[ks] = *(const bf16x8*)&Qt[((size_t)b * NN + iw + l15) * AC2 +
                                     ks * 32 + (lh << 3)];

    f32x4 acc[4][2];
#pragma unroll
    for (int f = 0; f < 4; ++f)
#pragma unroll
        for (int cf = 0; cf < 2; ++cf) acc[f][cf] = (f32x4){0.f, 0.f, 0.f, 0.f};

    // prefetch j-tile 0
    bf16x8 Kc[4][2], Vc[2][2];
    float tc[4];
#pragma unroll
    for (int jf = 0; jf < 4; ++jf) {
#pragma unroll
        for (int ks = 0; ks < 2; ++ks)
            Kc[jf][ks] = *(const bf16x8*)&Ktb[(size_t)(jf * 16 + l15) * AC2 +
                                              ks * 32 + (lh << 3)];
        tc[jf] = tb[jf * 16 + l15];
    }
#pragma unroll
    for (int cf = 0; cf < 2; ++cf)
#pragma unroll
        for (int ks = 0; ks < 2; ++ks)
            Vc[cf][ks] = *(const bf16x8*)&Vb[(size_t)(cf * 16 + l15) * NN +
                                             ks * 32 + (lh << 3)];

    for (int jt = 0; jt < 64; ++jt) {
        // issue next-tile prefetch early (wraps to tile 0 on last iter; harmless)
        const int jn = ((jt + 1) & 63) << 6;
        bf16x8 Kn[4][2], Vn[2][2];
        float tn[4];
#pragma unroll
        for (int jf = 0; jf < 4; ++jf) {
#pragma unroll
            for (int ks = 0; ks < 2; ++ks)
                Kn[jf][ks] = *(const bf16x8*)&Ktb[(size_t)(jn + jf * 16 + l15) * AC2 +
                                                  ks * 32 + (lh << 3)];
            tn[jf] = tb[jn + jf * 16 + l15];
        }
#pragma unroll
        for (int cf = 0; cf < 2; ++cf)
#pragma unroll
            for (int ks = 0; ks < 2; ++ks)
                Vn[cf][ks] = *(const bf16x8*)&Vb[(size_t)(cf * 16 + l15) * NN + jn +
                                                 ks * 32 + (lh << 3)];

        // S phase: this wave's 16 rows x 64 cols -> exp -> P[buf]
        short* Plw = &Pl[jt & 1][0];
#pragma unroll
        for (int jf = 0; jf < 4; ++jf) {
            f32x4 s = (f32x4){0.f, 0.f, 0.f, 0.f};
            s = __builtin_amdgcn_mfma_f32_16x16x32_bf16(Aq[0], Kc[jf][0], s, 0, 0, 0);
            s = __builtin_amdgcn_mfma_f32_16x16x32_bf16(Aq[1], Kc[jf][1], s, 0, 0, 0);
#pragma unroll
            for (int r = 0; r < 4; ++r)
                Plw[(w * 16 + lh * 4 + r) * PP + jf * 16 + l15] =
                    f2bf(__expf(s[r] - tc[jf]));
        }
        // lgkm-only drain + raw barrier: global prefetch stays in flight
        asm volatile("s_waitcnt lgkmcnt(0)" ::: "memory");
        __builtin_amdgcn_s_barrier();
        asm volatile("" ::: "memory");
        // PV phase: full 64-row P x this wave's 32-c V strip
#pragma unroll
        for (int ks = 0; ks < 2; ++ks) {
#pragma unroll
            for (int f = 0; f < 4; ++f) {
                bf16x8 Ap = *(const bf16x8*)&Plw[(f * 16 + l15) * PP +
                                                 ks * 32 + (lh << 3)];
#pragma unroll
                for (int cf = 0; cf < 2; ++cf)
                    acc[f][cf] = __builtin_amdgcn_mfma_f32_16x16x32_bf16(
                        Ap, Vc[cf][ks], acc[f][cf], 0, 0, 0);
            }
        }
        // rotate prefetch buffers
#pragma unroll
        for (int jf = 0; jf < 4; ++jf) {
            Kc[jf][0] = Kn[jf][0]; Kc[jf][1] = Kn[jf][1]; tc[jf] = tn[jf];
        }
#pragma unroll
        for (int cf = 0; cf < 2; ++cf) { Vc[cf][0] = Vn[cf][0]; Vc[cf][1] = Vn[cf][1]; }
    }

    // epilogue: per-wave LDS transpose (reuses Pl) -> coalesced 16B out writes
    __syncthreads();   // all PV reads of Pl complete before reuse
    const float g = gamma[0];
    float* Pfw = (float*)&Pl[0][0] + w * 1056;   // 32c x 32i, pitch 33
#pragma unroll
    for (int pass = 0; pass < 2; ++pass) {
#pragma unroll
        for (int fh = 0; fh < 2; ++fh) {
            const int f = pass * 2 + fh;
#pragma unroll
            for (int cf = 0; cf < 2; ++cf)
#pragma unroll
                for (int r = 0; r < 4; ++r)
                    Pfw[(cf * 16 + l15) * 33 + fh * 16 + lh * 4 + r] = acc[f][cf][r];
        }
        // wave-private region: in-wave lgkm ordering suffices (no barrier)
#pragma unroll
        for (int cq = 0; cq < 4; ++cq) {
            const int c = cq * 8 + (lane >> 3);
            const int iq = (lane & 7) * 4;
            float4 v;
            v.x = Pfw[c * 33 + iq + 0];
            v.y = Pfw[c * 33 + iq + 1];
            v.z = Pfw[c * 33 + iq + 2];
            v.w = Pfw[c * 33 + iq + 3];
            const size_t gidx = ((size_t)(b * CC + c0 + w * 32 + c)) * NN +
                                i0 + pass * 32 + iq;
            float4 xv = *(const float4*)&x[gidx];
            float4 o;
            o.x = g * v.x + xv.x;
            o.y = g * v.y + xv.y;
            o.z = g * v.z + xv.z;
            o.w = g * v.w + xv.w;
            *(float4*)&out[gidx] = o;
        }
    }
}

extern "C" void kernel_launch(void* const* d_in, const int* in_sizes, int n_in,
                              void* d_out, int out_size, void* d_ws, size_t ws_size,
                              hipStream_t stream) {
    const float* x     = (const float*)d_in[0];
    const float* Wq    = (const float*)d_in[1];
    const float* bq    = (const float*)d_in[2];
    const float* Wk    = (const float*)d_in[3];
    const float* bk    = (const float*)d_in[4];
    const float* Wv    = (const float*)d_in[5];
    const float* bv    = (const float*)d_in[6];
    const float* gamma = (const float*)d_in[7];
    float* out = (float*)d_out;

    short* Qt = (short*)d_ws;                            // [B][N][64] bf16 (2 MB)
    short* Kt = Qt + (size_t)BB * NN * AC2;              // [B][N][64] bf16 (2 MB)
    short* V  = Kt + (size_t)BB * NN * AC2;              // [B][C][N]  bf16 (8 MB)
    float* tArr = (float*)(V + (size_t)BB * CC * NN);    // [B][N]     f32  (64 KB)
    short* Wb = (short*)(tArr + (size_t)BB * NN);        // [384][256] bf16 (192 KB)

    prep_kernel<<<96, 256, 0, stream>>>(Wq, Wk, Wv, Wb);
    qkv_kernel<<<BB * 128, 512, 0, stream>>>(x, Wb, bq, bk, bv, Qt, Kt, V);
    stats_kernel<<<BB * 256, 256, 0, stream>>>(Qt, Kt, tArr);
    out_kernel<<<BB * 128, 256, 0, stream>>>(Qt, Kt, V, tArr, x, gamma, out);
}